// Round 4
// baseline (249.705 us; speedup 1.0000x reference)
//
#include <hip/hip_runtime.h>

typedef unsigned short u16;
typedef unsigned int u32;
using f32x4  = __attribute__((ext_vector_type(4))) float;
using short8 = __attribute__((ext_vector_type(8))) short;
using s16x4  = __attribute__((ext_vector_type(4))) short;
using u16x4  = __attribute__((ext_vector_type(4))) unsigned short;

#define DEV __device__ __forceinline__

DEV u16 f2bf(float f) {
  u32 u = __float_as_uint(f);
  u32 r = u + 0x7fffu + ((u >> 16) & 1u);
  return (u16)(r >> 16);
}

DEV void gload_lds16(const void* g, void* l) {
  __builtin_amdgcn_global_load_lds(
      (__attribute__((address_space(1))) void*)g,
      (__attribute__((address_space(3))) void*)l, 16, 0, 0);
}

DEV void block_reduce2(float& a, float& b, float* red) {
#pragma unroll
  for (int m = 1; m < 64; m <<= 1) {
    a += __shfl_xor(a, m);
    b += __shfl_xor(b, m);
  }
  const int wid = threadIdx.x >> 6, lane = threadIdx.x & 63;
  __syncthreads();
  if (lane == 0) { red[wid] = a; red[4 + wid] = b; }
  __syncthreads();
  a = red[0] + red[1] + red[2] + red[3];
  b = red[4] + red[5] + red[6] + red[7];
}

// ---------------- LayerNorm rows: f32 [rows][1024] -> bf16 into xnl ----------------
__global__ __launch_bounds__(256) void ln_rows_k(
    const float* __restrict__ X, const float* __restrict__ g,
    const float* __restrict__ be, u16* __restrict__ out, int mode)
{
  __shared__ float red[8];
  const int r = blockIdx.x, t = threadIdx.x;
  const float4 v = *(const float4*)(X + (((size_t)r) << 10) + t * 4);
  float s1 = v.x + v.y + v.z + v.w;
  float s2 = v.x * v.x + v.y * v.y + v.z * v.z + v.w * v.w;
  block_reduce2(s1, s2, red);
  const float mean = s1 * (1.f / 1024.f);
  const float var  = s2 * (1.f / 1024.f) - mean * mean;
  const float rstd = rsqrtf(var + 1e-5f);
  const float4 gv = *(const float4*)(g + t * 4);
  const float4 bv = *(const float4*)(be + t * 4);
  u16x4 o;
  o[0] = f2bf((v.x - mean) * rstd * gv.x + bv.x);
  o[1] = f2bf((v.y - mean) * rstd * gv.y + bv.y);
  o[2] = f2bf((v.z - mean) * rstd * gv.z + bv.z);
  o[3] = f2bf((v.w - mean) * rstd * gv.w + bv.w);
  const size_t orow = (mode == 0)
      ? ((size_t)(r >> 12) * 4160 + (r & 4095))
      : ((size_t)(r >> 6) * 4160 + 4096 + (r & 63));
  *(u16x4*)(out + orow * 1024 + t * 4) = o;
}

// ---------------- weight transpose + bf16 cast: W[K][N] f32 -> Wt[N][K] bf16 ----------------
__global__ __launch_bounds__(256) void transpose_w_k(
    const float* __restrict__ W, u16* __restrict__ Wt, int K, int N)
{
  __shared__ float tile[32][33];
  const int n0 = blockIdx.x * 32, k0 = blockIdx.y * 32;
  const int tx = threadIdx.x, ty = threadIdx.y;
#pragma unroll
  for (int i = 0; i < 4; ++i)
    tile[ty + 8 * i][tx] = W[(size_t)(k0 + ty + 8 * i) * N + n0 + tx];
  __syncthreads();
#pragma unroll
  for (int i = 0; i < 4; ++i)
    Wt[(size_t)(n0 + ty + 8 * i) * K + k0 + tx] = f2bf(tile[tx][ty + 8 * i]);
}

// ---------------- mask -> additive bias [8][4160], with dtype sniffing ----------------
__global__ __launch_bounds__(256) void mask_bias_k(const void* __restrict__ mask,
                                                   float* __restrict__ bias)
{
  __shared__ int flag_s;
  if (threadIdx.x == 0) {
    const u32* mw = (const u32*)mask;
    bool fpat = true, ipat = true;
    for (int i = 0; i < 256; ++i) {
      u32 w = mw[i];
      if (w != 0u && w != 0x3f800000u) fpat = false;
      if (w > 1u) ipat = false;
    }
    flag_s = fpat ? 2 : (ipat ? 1 : 0);
  }
  __syncthreads();
  const int flag = flag_s;
  const int idx = blockIdx.x * 256 + threadIdx.x;  // 0..33279 exactly
  const int b = idx / 4160, j = idx - b * 4160;
  float bv = 0.f;
  if (j < 4096) {
    const int mi = b * 4096 + j;
    bool on;
    if (flag == 2)      on = ((const float*)mask)[mi] != 0.f;
    else if (flag == 1) on = ((const int*)mask)[mi] != 0;
    else                on = ((const unsigned char*)mask)[mi] != 0;
    bv = on ? 0.f : -1e30f;
  }
  bias[idx] = bv;
}

// ---------------- fused 8-phase 256x256 bf16 GEMM (m201 structure, hoisted addr) ----------------
// One launch, 524 blocks:
//   [0,260)   mode0: k   = xnl(33280x1024) @ WkT(512x1024)^T   -> k_h [b][h][j][d]
//   [260,520) mode2: v^T = WvT(512x1024)  @ xnl(33280x1024)^T  -> v_t [b][h][d][j]
//   [520,524) mode1: q   = ln(512 latent rows) @ WqT(512x1024)^T -> q_h [b][h][i][d]
__global__ __launch_bounds__(512, 2) void gemm8_k(
    const u16* __restrict__ xnl, const u16* __restrict__ Wq_t,
    const u16* __restrict__ Wkv_t,
    u16* __restrict__ q_h, u16* __restrict__ k_h, u16* __restrict__ v_t)
{
  __shared__ __attribute__((aligned(16))) short As[2][16384];
  __shared__ __attribute__((aligned(16))) short Bs[2][16384];

  const int tid = threadIdx.x, wid = tid >> 6, lane = tid & 63;
  const int wr = wid >> 2, wc = wid & 3;
  const int l15 = lane & 15, lq = lane >> 4;

  const int bid = blockIdx.x;
  int mode, mblk, nblk;
  const u16 *Ap, *Bp;
  if (bid < 260)      { mode = 0; mblk = bid % 130; nblk = bid / 130; Ap = xnl; Bp = Wkv_t; }
  else if (bid < 520) { const int r2 = bid - 260; mode = 2; mblk = r2 / 130; nblk = r2 % 130;
                        Ap = Wkv_t + (size_t)512 * 1024; Bp = xnl; }
  else                { const int r2 = bid - 520; mode = 1; mblk = r2 >> 1; nblk = r2 & 1;
                        Ap = xnl; Bp = Wq_t; }
  const int m0 = mblk * 256, n0 = nblk * 256;
  const bool remap = (mode == 1);

  // ---- hoisted per-thread stage constants (t-independent) ----
  // granule j in {0..3} = (half=j>>1, i=j&1): row = half*128 + i*64 + tid>>3, slot = tid&7
  u32 asrc[4], bsrc[4];
  int ldsoff[4];
#pragma unroll
  for (int j = 0; j < 4; ++j) {
    const int half = j >> 1, ii = j & 1;
    const int rowc = half * 128 + ii * 64 + (tid >> 3);
    const int slot = tid & 7;
    const int gr = m0 + rowc;
    const u32 arow = remap ? ((u32)(gr >> 6) * 4160 + 4096 + (gr & 63)) : (u32)gr;
    asrc[j] = arow * 1024u + (u32)((slot ^ (rowc & 7)) * 8);
    bsrc[j] = (u32)(n0 + rowc) * 1024u + (u32)((slot ^ (rowc & 7)) * 8);
    ldsoff[j] = half * 8192 + ii * 4096 + wid * 512;   // elements
  }
  auto stageA = [&](int c, int T, int j) {
    gload_lds16(Ap + asrc[j] + (u32)T * 64u, &As[c][ldsoff[j]]);
  };
  auto stageB = [&](int c, int T, int j) {
    gload_lds16(Bp + bsrc[j] + (u32)T * 64u, &Bs[c][ldsoff[j]]);
  };

  // ---- hoisted per-thread read constants ----
  // readA(c,H,mi,w) byte = c*32768 + (wr*64+l15)*128 + H*16384 + mi*2048 + vaw
  const int swz = (l15 & 7) << 4;
  const int va0 = (lq * 16) ^ swz;
  const int va1 = (64 + lq * 16) ^ swz;
  const char* ArdBase = (const char*)&As[0][0] + (wr * 64 + l15) * 128;
  const char* BrdBase = (const char*)&Bs[0][0] + (wc * 32 + l15) * 128;

  const f32x4 z4 = {0.f, 0.f, 0.f, 0.f};
  f32x4 acc[8][4];
#pragma unroll
  for (int i = 0; i < 8; ++i)
#pragma unroll
    for (int j = 0; j < 4; ++j) acc[i][j] = z4;

  // prologue: stage tiles 0 and 1 (8 loads each, tile0 first)
#pragma unroll
  for (int T = 0; T < 2; ++T) {
    stageA(T, T, 0); stageA(T, T, 1);
    stageB(T, T, 0); stageB(T, T, 1);
    stageB(T, T, 2); stageB(T, T, 3);
    stageA(T, T, 2); stageA(T, T, 3);
  }
  asm volatile("s_waitcnt vmcnt(8)" ::: "memory");
  __builtin_amdgcn_s_barrier();

  short8 af[4][2], bf0[2][2], bf1[2][2];

#pragma unroll 1
  for (int t = 0; t < 16; ++t) {
    const int c = t & 1;
    const char* Ac = ArdBase + c * 32768;
    const char* Bc = BrdBase + c * 32768;

    // ---- P1: read A-h0 (8) + B-h0 (4); MFMA Q(m0,n0)
#pragma unroll
    for (int mi = 0; mi < 4; ++mi) {
      af[mi][0] = *(const short8*)(Ac + mi * 2048 + va0);
      af[mi][1] = *(const short8*)(Ac + mi * 2048 + va1);
    }
#pragma unroll
    for (int nj = 0; nj < 2; ++nj) {
      bf0[nj][0] = *(const short8*)(Bc + nj * 2048 + va0);
      bf0[nj][1] = *(const short8*)(Bc + nj * 2048 + va1);
    }
    __builtin_amdgcn_s_barrier();
    asm volatile("s_waitcnt lgkmcnt(0)" ::: "memory");
    __builtin_amdgcn_sched_barrier(0);
    __builtin_amdgcn_s_setprio(1);
#pragma unroll
    for (int mi = 0; mi < 4; ++mi)
#pragma unroll
      for (int nj = 0; nj < 2; ++nj)
#pragma unroll
        for (int w = 0; w < 2; ++w)
          acc[mi][nj] = __builtin_amdgcn_mfma_f32_16x16x32_bf16(af[mi][w], bf0[nj][w], acc[mi][nj], 0, 0, 0);
    __builtin_amdgcn_s_setprio(0);
    __builtin_amdgcn_s_barrier();

    // ---- P2: read B-h1 (4); stage A-h0,B-h0 of t+2; MFMA Q(m0,n1)
#pragma unroll
    for (int nj = 0; nj < 2; ++nj) {
      bf1[nj][0] = *(const short8*)(Bc + 16384 + nj * 2048 + va0);
      bf1[nj][1] = *(const short8*)(Bc + 16384 + nj * 2048 + va1);
    }
    if (t < 14) {
      stageA(c, t + 2, 0); stageA(c, t + 2, 1);
      stageB(c, t + 2, 0); stageB(c, t + 2, 1);
    }
    __builtin_amdgcn_s_barrier();
    asm volatile("s_waitcnt lgkmcnt(0)" ::: "memory");
    __builtin_amdgcn_sched_barrier(0);
    __builtin_amdgcn_s_setprio(1);
#pragma unroll
    for (int mi = 0; mi < 4; ++mi)
#pragma unroll
      for (int nj = 0; nj < 2; ++nj)
#pragma unroll
        for (int w = 0; w < 2; ++w)
          acc[mi][2 + nj] = __builtin_amdgcn_mfma_f32_16x16x32_bf16(af[mi][w], bf1[nj][w], acc[mi][2 + nj], 0, 0, 0);
    __builtin_amdgcn_s_setprio(0);
    __builtin_amdgcn_s_barrier();

    // ---- P3: read A-h1 (8, overwrite af); stage B-h1 of t+2; MFMA Q(m1,n0)
#pragma unroll
    for (int mi = 0; mi < 4; ++mi) {
      af[mi][0] = *(const short8*)(Ac + 16384 + mi * 2048 + va0);
      af[mi][1] = *(const short8*)(Ac + 16384 + mi * 2048 + va1);
    }
    if (t < 14) { stageB(c, t + 2, 2); stageB(c, t + 2, 3); }
    __builtin_amdgcn_s_barrier();
    asm volatile("s_waitcnt lgkmcnt(0)" ::: "memory");
    __builtin_amdgcn_sched_barrier(0);
    __builtin_amdgcn_s_setprio(1);
#pragma unroll
    for (int mi = 0; mi < 4; ++mi)
#pragma unroll
      for (int nj = 0; nj < 2; ++nj)
#pragma unroll
        for (int w = 0; w < 2; ++w)
          acc[4 + mi][nj] = __builtin_amdgcn_mfma_f32_16x16x32_bf16(af[mi][w], bf0[nj][w], acc[4 + mi][nj], 0, 0, 0);
    __builtin_amdgcn_s_setprio(0);
    __builtin_amdgcn_s_barrier();

    // ---- P4: stage A-h1 of t+2; MFMA Q(m1,n1); vmcnt before closing barrier
    if (t < 14) { stageA(c, t + 2, 2); stageA(c, t + 2, 3); }
    __builtin_amdgcn_s_barrier();
    __builtin_amdgcn_s_setprio(1);
#pragma unroll
    for (int mi = 0; mi < 4; ++mi)
#pragma unroll
      for (int nj = 0; nj < 2; ++nj)
#pragma unroll
        for (int w = 0; w < 2; ++w)
          acc[4 + mi][2 + nj] = __builtin_amdgcn_mfma_f32_16x16x32_bf16(af[mi][w], bf1[nj][w], acc[4 + mi][2 + nj], 0, 0, 0);
    __builtin_amdgcn_s_setprio(0);
    if (t < 14)      { asm volatile("s_waitcnt vmcnt(8)" ::: "memory"); }
    else if (t == 14){ asm volatile("s_waitcnt vmcnt(0)" ::: "memory"); }
    __builtin_amdgcn_s_barrier();
  }

  // ---- epilogue
#pragma unroll
  for (int ai = 0; ai < 8; ++ai) {
    const int mh = ai >> 2, mi = ai & 3;
#pragma unroll
    for (int bi = 0; bi < 4; ++bi) {
      const int nh = bi >> 1, nj = bi & 1;
      const int gn = n0 + nh * 128 + wc * 32 + nj * 16 + l15;
#pragma unroll
      for (int r = 0; r < 4; ++r) {
        const int gm = m0 + mh * 128 + wr * 64 + mi * 16 + lq * 4 + r;
        const u16 v = f2bf(acc[ai][bi][r]);
        if (mode == 0) {
          const int b = gm / 4160, j = gm - b * 4160;
          k_h[(((size_t)b * 8 + (gn >> 6)) * 4160 + j) * 64 + (gn & 63)] = v;
        } else if (mode == 2) {
          const int b = gn / 4160, j = gn - b * 4160;
          v_t[(((size_t)b * 8 + (gm >> 6)) * 64 + (gm & 63)) * 4160 + j] = v;
        } else {
          const int b = gm >> 6, i2 = gm & 63;
          q_h[(((size_t)b * 8 + (gn >> 6)) * 64 + i2) * 64 + (gn & 63)] = v;
        }
      }
    }
  }
}

// ---------------- flash attention, 512 blocks = (b,h) x 8 kv-splits ----------------
// S^T = K*q^T (so per-lane softmax state is one q row), O^T = V^T * P.
__global__ __launch_bounds__(256) void attn_k(
    const u16* __restrict__ q_h, const u16* __restrict__ k_h,
    const u16* __restrict__ v_t, const float* __restrict__ bias,
    float* __restrict__ O_part, float* __restrict__ m_part,
    float* __restrict__ l_part)
{
  __shared__ __attribute__((aligned(16))) short Ks[4096];   // swizzled [kv][d]
  __shared__ __attribute__((aligned(16))) short Vs[4096];   // swizzled [d][kv]
  __shared__ __attribute__((aligned(16))) short Ps[4][1152]; // per-wave P[q][kv], stride 72
  __shared__ float biasS[64];
  const int bid = blockIdx.x;
  const int sp = bid & 7, bh = bid >> 3;
  const int b = bh >> 3;
  const int tid = threadIdx.x, wid = tid >> 6, lane = tid & 63;
  const int t0 = sp ? (8 * sp + 1) : 0;
  const int tc = sp ? 8 : 9;                 // 9 + 7*8 = 65 tiles of 64 kv

  const size_t qoff = ((size_t)bh * 64 + wid * 16 + (lane & 15)) * 64 + 8 * (lane >> 4);
  const short8 qf0 = *(const short8*)&q_h[qoff];
  const short8 qf1 = *(const short8*)&q_h[qoff + 32];

  float mrun = -1e30f, lrun = 0.f;
  const f32x4 z4 = {0.f, 0.f, 0.f, 0.f};
  f32x4 o[4] = {z4, z4, z4, z4};
  const size_t khead = (size_t)bh * (4160 * 64);
  const size_t vhead = (size_t)bh * (64 * 4160);

  for (int tt = 0; tt < tc; ++tt) {
    const int t = t0 + tt;
    // stage K tile [64 kv][64 d], XOR-swizzled via pre-swizzled global source
#pragma unroll
    for (int p = 0; p < 2; ++p) {
      const int lo = (p * 256 + tid) * 16;
      const int row = lo >> 7;
      const int src = lo ^ ((row & 7) << 4);
      gload_lds16((const char*)k_h + (khead + (size_t)t * 4096) * 2 + src,
                  (char*)Ks + (p * 256 + wid * 64) * 16);
    }
    // stage V^T tile [64 d][64 kv] from v_t (row stride 4160)
#pragma unroll
    for (int p = 0; p < 2; ++p) {
      const int lo = (p * 256 + tid) * 16;
      const int row = lo >> 7;
      const int colb = (lo ^ ((row & 7) << 4)) & 127;
      gload_lds16((const char*)v_t + (vhead + (size_t)row * 4160 + t * 64) * 2 + colb,
                  (char*)Vs + (p * 256 + wid * 64) * 16);
    }
    if (tid < 64) biasS[tid] = bias[b * 4160 + t * 64 + tid];
    __syncthreads();

    // S^T = K * q^T : D[kv][q], kv = mi*16 + (lane>>4)*4 + r, q = lane&15
    f32x4 sc[4] = {z4, z4, z4, z4};
#pragma unroll
    for (int mi = 0; mi < 4; ++mi) {
      const int row = mi * 16 + (lane & 15);
      const int sw = (row & 7) << 4;
      short8 a0 = *(const short8*)((const char*)Ks + ((row * 128 + 16 * (lane >> 4)) ^ sw));
      sc[mi] = __builtin_amdgcn_mfma_f32_16x16x32_bf16(a0, qf0, sc[mi], 0, 0, 0);
      short8 a1 = *(const short8*)((const char*)Ks + ((row * 128 + 64 + 16 * (lane >> 4)) ^ sw));
      sc[mi] = __builtin_amdgcn_mfma_f32_16x16x32_bf16(a1, qf1, sc[mi], 0, 0, 0);
    }

    float sv[4][4];
    float tmax = -3e30f;
#pragma unroll
    for (int mi = 0; mi < 4; ++mi)
#pragma unroll
      for (int r = 0; r < 4; ++r) {
        const int kv = mi * 16 + (lane >> 4) * 4 + r;
        const float s = sc[mi][r] * (1.f / 64.f) + biasS[kv];
        sv[mi][r] = s;
        tmax = fmaxf(tmax, s);
      }
    tmax = fmaxf(tmax, __shfl_xor(tmax, 16));
    tmax = fmaxf(tmax, __shfl_xor(tmax, 32));
    const float mnew = fmaxf(mrun, tmax);
    const float fac = __expf(mrun - mnew);
    float psum = 0.f;
#pragma unroll
    for (int mi = 0; mi < 4; ++mi) {
      s16x4 pk;
#pragma unroll
      for (int r = 0; r < 4; ++r) {
        const float p = __expf(sv[mi][r] - mnew);
        psum += p;
        pk[r] = (short)f2bf(p);
      }
      *(s16x4*)&Ps[wid][(lane & 15) * 72 + mi * 16 + (lane >> 4) * 4] = pk;
    }
    psum += __shfl_xor(psum, 16);
    psum += __shfl_xor(psum, 32);
    lrun = lrun * fac + psum;
    mrun = mnew;
#pragma unroll
    for (int mi = 0; mi < 4; ++mi)
#pragma unroll
      for (int e = 0; e < 4; ++e) o[mi][e] *= fac;

    // O^T += V^T * P : D[d][q], d = mi*16 + (lane>>4)*4 + r, q = lane&15
#pragma unroll
    for (int mi = 0; mi < 4; ++mi) {
      const int row = mi * 16 + (lane & 15);
      const int sw = (row & 7) << 4;
      short8 a0 = *(const short8*)((const char*)Vs + ((row * 128 + 16 * (lane >> 4)) ^ sw));
      short8 p0 = *(const short8*)&Ps[wid][(lane & 15) * 72 + 8 * (lane >> 4)];
      o[mi] = __builtin_amdgcn_mfma_f32_16x16x32_bf16(a0, p0, o[mi], 0, 0, 0);
      short8 a1 = *(const short8*)((const char*)Vs + ((row * 128 + 64 + 16 * (lane >> 4)) ^ sw));
      short8 p1 = *(const short8*)&Ps[wid][(lane & 15) * 72 + 32 + 8 * (lane >> 4)];
      o[mi] = __builtin_amdgcn_mfma_f32_16x16x32_bf16(a1, p1, o[mi], 0, 0, 0);
    }
    __syncthreads();
  }

#pragma unroll
  for (int mi = 0; mi < 4; ++mi)
#pragma unroll
    for (int r = 0; r < 4; ++r) {
      const int d = mi * 16 + (lane >> 4) * 4 + r;
      const int q = wid * 16 + (lane & 15);
      O_part[(((size_t)sp * 64 + bh) * 64 + d) * 64 + q] = o[mi][r];
    }
  if (lane < 16) {
    m_part[((size_t)sp * 64 + bh) * 64 + wid * 16 + lane] = mrun;
    l_part[((size_t)sp * 64 + bh) * 64 + wid * 16 + lane] = lrun;
  }
}

// ---------------- split-softmax combine -> attn_out [b][i][h*64+d] f32 ----------------
__global__ __launch_bounds__(256) void combine_k(
    const float* __restrict__ O_part, const float* __restrict__ m_part,
    const float* __restrict__ l_part, float* __restrict__ attn_out)
{
  __shared__ float wgt[8][64];
  const int bh = blockIdx.x;
  const int b = bh >> 3, h = bh & 7;
  const int t = threadIdx.x;
  if (t < 64) {
    float mv[8], lv[8];
#pragma unroll
    for (int s = 0; s < 8; ++s) {
      mv[s] = m_part[((size_t)s * 64 + bh) * 64 + t];
      lv[s] = l_part[((size_t)s * 64 + bh) * 64 + t];
    }
    float M = mv[0];
#pragma unroll
    for (int s = 1; s < 8; ++s) M = fmaxf(M, mv[s]);
    float den = 0.f;
#pragma unroll
    for (int s = 0; s < 8; ++s) den += lv[s] * __expf(mv[s] - M);
    const float inv = 1.f / den;
#pragma unroll
    for (int s = 0; s < 8; ++s) wgt[s][t] = __expf(mv[s] - M) * inv;
  }
  __syncthreads();
#pragma unroll
  for (int i = 0; i < 16; ++i) {
    const int p = i * 256 + t;
    const int d = p >> 6, q = p & 63;
    float acc = 0.f;
#pragma unroll
    for (int s = 0; s < 8; ++s)
      acc += O_part[(((size_t)s * 64 + bh) * 64 + d) * 64 + q] * wgt[s][q];
    attn_out[((size_t)b * 64 + q) * 512 + h * 64 + d] = acc;
  }
}

// ---------------- out = LN(attn_out @ Wo), 2 rows per block ----------------
__global__ __launch_bounds__(256) void outproj_k(
    const float* __restrict__ attn_out, const float* __restrict__ Wo,
    const float* __restrict__ g, const float* __restrict__ be,
    float* __restrict__ out)
{
  __shared__ float arow[2][512];
  __shared__ float red[8];
  const int rb = blockIdx.x * 2, t = threadIdx.x;
  arow[0][t]       = attn_out[(size_t)rb * 512 + t];
  arow[0][t + 256] = attn_out[(size_t)rb * 512 + 256 + t];
  arow[1][t]       = attn_out[(size_t)(rb + 1) * 512 + t];
  arow[1][t + 256] = attn_out[(size_t)(rb + 1) * 512 + 256 + t];
  __syncthreads();
  float a0x = 0, a0y = 0, a0z = 0, a0w = 0;
  float a1x = 0, a1y = 0, a1z = 0, a1w = 0;
  for (int k = 0; k < 512; ++k) {
    const float4 w = *(const float4*)(Wo + (size_t)k * 1024 + t * 4);
    const float x0 = arow[0][k], x1 = arow[1][k];
    a0x += x0 * w.x; a0y += x0 * w.y; a0z += x0 * w.z; a0w += x0 * w.w;
    a1x += x1 * w.x; a1y += x1 * w.y; a1z += x1 * w.z; a1w += x1 * w.w;
  }
  const float4 gv = *(const float4*)(g + t * 4);
  const float4 bv = *(const float4*)(be + t * 4);
  {
    float s1 = a0x + a0y + a0z + a0w;
    float s2 = a0x * a0x + a0y * a0y + a0z * a0z + a0w * a0w;
    block_reduce2(s1, s2, red);
    const float mean = s1 * (1.f / 1024.f);
    const float rstd = rsqrtf(s2 * (1.f / 1024.f) - mean * mean + 1e-5f);
    float4 ov;
    ov.x = (a0x - mean) * rstd * gv.x + bv.x;
    ov.y = (a0y - mean) * rstd * gv.y + bv.y;
    ov.z = (a0z - mean) * rstd * gv.z + bv.z;
    ov.w = (a0w - mean) * rstd * gv.w + bv.w;
    *(float4*)(out + (size_t)rb * 1024 + t * 4) = ov;
  }
  {
    float s1 = a1x + a1y + a1z + a1w;
    float s2 = a1x * a1x + a1y * a1y + a1z * a1z + a1w * a1w;
    block_reduce2(s1, s2, red);
    const float mean = s1 * (1.f / 1024.f);
    const float rstd = rsqrtf(s2 * (1.f / 1024.f) - mean * mean + 1e-5f);
    float4 ov;
    ov.x = (a1x - mean) * rstd * gv.x + bv.x;
    ov.y = (a1y - mean) * rstd * gv.y + bv.y;
    ov.z = (a1z - mean) * rstd * gv.z + bv.z;
    ov.w = (a1w - mean) * rstd * gv.w + bv.w;
    *(float4*)(out + (size_t)(rb + 1) * 1024 + t * 4) = ov;
  }
}

extern "C" void kernel_launch(void* const* d_in, const int* in_sizes, int n_in,
                              void* d_out, int out_size, void* d_ws, size_t ws_size,
                              hipStream_t stream) {
  (void)in_sizes; (void)n_in; (void)out_size; (void)ws_size;
  const float* x       = (const float*)d_in[0];
  const float* latents = (const float*)d_in[1];
  const void*  mask    = d_in[2];
  const float* Wq      = (const float*)d_in[3];
  const float* Wkv     = (const float*)d_in[4];
  const float* Wo      = (const float*)d_in[5];
  const float* gx      = (const float*)d_in[6];
  const float* bx      = (const float*)d_in[7];
  const float* gl      = (const float*)d_in[8];
  const float* bl      = (const float*)d_in[9];
  const float* go      = (const float*)d_in[10];
  const float* bo      = (const float*)d_in[11];
  float* out = (float*)d_out;

  char* w = (char*)d_ws;
  u16* xnl   = (u16*)w; w += (size_t)33280 * 1024 * 2;       // LN'd concat rows, bf16
  u16* Wq_t  = (u16*)w; w += (size_t)512 * 1024 * 2;         // Wq^T bf16
  u16* Wkv_t = (u16*)w; w += (size_t)1024 * 1024 * 2;        // Wkv^T bf16
  u16* q_h   = (u16*)w; w += (size_t)8 * 8 * 64 * 64 * 2;    // [b][h][i][d]
  u16* k_h   = (u16*)w; w += (size_t)8 * 8 * 4160 * 64 * 2;  // [b][h][j][d]
  u16* v_t   = (u16*)w; w += (size_t)8 * 8 * 64 * 4160 * 2;  // [b][h][d][j]
  float* bias   = (float*)w; w += (size_t)8 * 4160 * 4;
  float* O_part = (float*)w; w += (size_t)8 * 64 * 64 * 64 * 4;
  float* m_part = (float*)w; w += (size_t)8 * 64 * 64 * 4;
  float* l_part = (float*)w; w += (size_t)8 * 64 * 64 * 4;
  float* attnO  = (float*)w; w += (size_t)512 * 512 * 4;

  transpose_w_k<<<dim3(16, 32), dim3(32, 8), 0, stream>>>(Wq, Wq_t, 1024, 512);
  transpose_w_k<<<dim3(32, 32), dim3(32, 8), 0, stream>>>(Wkv, Wkv_t, 1024, 1024);
  ln_rows_k<<<dim3(32768), dim3(256), 0, stream>>>(x, gx, bx, xnl, 0);
  ln_rows_k<<<dim3(512), dim3(256), 0, stream>>>(latents, gl, bl, xnl, 1);
  mask_bias_k<<<dim3(130), dim3(256), 0, stream>>>(mask, bias);
  gemm8_k<<<dim3(524), dim3(512), 0, stream>>>(xnl, Wq_t, Wkv_t, q_h, k_h, v_t);
  attn_k<<<dim3(512), dim3(256), 0, stream>>>(q_h, k_h, v_t, bias, O_part, m_part, l_part);
  combine_k<<<dim3(64), dim3(256), 0, stream>>>(O_part, m_part, l_part, attnO);
  outproj_k<<<dim3(256), dim3(256), 0, stream>>>(attnO, Wo, go, bo, out);
}

// Round 5
// 245.081 us; speedup vs baseline: 1.0189x; 1.0189x over previous
//
#include <hip/hip_runtime.h>

typedef unsigned short u16;
typedef unsigned int u32;
using f32x4  = __attribute__((ext_vector_type(4))) float;
using short8 = __attribute__((ext_vector_type(8))) short;
using s16x4  = __attribute__((ext_vector_type(4))) short;
using u16x4  = __attribute__((ext_vector_type(4))) unsigned short;

#define DEV __device__ __forceinline__

DEV u16 f2bf(float f) {
  u32 u = __float_as_uint(f);
  u32 r = u + 0x7fffu + ((u >> 16) & 1u);
  return (u16)(r >> 16);
}

DEV void gload_lds16(const void* g, void* l) {
  __builtin_amdgcn_global_load_lds(
      (__attribute__((address_space(1))) void*)g,
      (__attribute__((address_space(3))) void*)l, 16, 0, 0);
}

DEV void block_reduce2(float& a, float& b, float* red) {
#pragma unroll
  for (int m = 1; m < 64; m <<= 1) {
    a += __shfl_xor(a, m);
    b += __shfl_xor(b, m);
  }
  const int wid = threadIdx.x >> 6, lane = threadIdx.x & 63;
  __syncthreads();
  if (lane == 0) { red[wid] = a; red[4 + wid] = b; }
  __syncthreads();
  a = red[0] + red[1] + red[2] + red[3];
  b = red[4] + red[5] + red[6] + red[7];
}

// ---------------- LayerNorm rows: f32 [rows][1024] -> bf16 into xnl ----------------
__global__ __launch_bounds__(256) void ln_rows_k(
    const float* __restrict__ X, const float* __restrict__ g,
    const float* __restrict__ be, u16* __restrict__ out, int mode)
{
  __shared__ float red[8];
  const int r = blockIdx.x, t = threadIdx.x;
  const float4 v = *(const float4*)(X + (((size_t)r) << 10) + t * 4);
  float s1 = v.x + v.y + v.z + v.w;
  float s2 = v.x * v.x + v.y * v.y + v.z * v.z + v.w * v.w;
  block_reduce2(s1, s2, red);
  const float mean = s1 * (1.f / 1024.f);
  const float var  = s2 * (1.f / 1024.f) - mean * mean;
  const float rstd = rsqrtf(var + 1e-5f);
  const float4 gv = *(const float4*)(g + t * 4);
  const float4 bv = *(const float4*)(be + t * 4);
  u16x4 o;
  o[0] = f2bf((v.x - mean) * rstd * gv.x + bv.x);
  o[1] = f2bf((v.y - mean) * rstd * gv.y + bv.y);
  o[2] = f2bf((v.z - mean) * rstd * gv.z + bv.z);
  o[3] = f2bf((v.w - mean) * rstd * gv.w + bv.w);
  const size_t orow = (mode == 0)
      ? ((size_t)(r >> 12) * 4160 + (r & 4095))
      : ((size_t)(r >> 6) * 4160 + 4096 + (r & 63));
  *(u16x4*)(out + orow * 1024 + t * 4) = o;
}

// ---------------- weight transpose + bf16 cast: W[K][N] f32 -> Wt[N][K] bf16 ----------------
__global__ __launch_bounds__(256) void transpose_w_k(
    const float* __restrict__ W, u16* __restrict__ Wt, int K, int N)
{
  __shared__ float tile[32][33];
  const int n0 = blockIdx.x * 32, k0 = blockIdx.y * 32;
  const int tx = threadIdx.x, ty = threadIdx.y;
#pragma unroll
  for (int i = 0; i < 4; ++i)
    tile[ty + 8 * i][tx] = W[(size_t)(k0 + ty + 8 * i) * N + n0 + tx];
  __syncthreads();
#pragma unroll
  for (int i = 0; i < 4; ++i)
    Wt[(size_t)(n0 + ty + 8 * i) * K + k0 + tx] = f2bf(tile[tx][ty + 8 * i]);
}

// ---------------- mask -> additive bias [8][4160], with dtype sniffing ----------------
__global__ __launch_bounds__(256) void mask_bias_k(const void* __restrict__ mask,
                                                   float* __restrict__ bias)
{
  __shared__ int flag_s;
  if (threadIdx.x == 0) {
    const u32* mw = (const u32*)mask;
    bool fpat = true, ipat = true;
    for (int i = 0; i < 256; ++i) {
      u32 w = mw[i];
      if (w != 0u && w != 0x3f800000u) fpat = false;
      if (w > 1u) ipat = false;
    }
    flag_s = fpat ? 2 : (ipat ? 1 : 0);
  }
  __syncthreads();
  const int flag = flag_s;
  const int idx = blockIdx.x * 256 + threadIdx.x;  // 0..33279 exactly
  const int b = idx / 4160, j = idx - b * 4160;
  float bv = 0.f;
  if (j < 4096) {
    const int mi = b * 4096 + j;
    bool on;
    if (flag == 2)      on = ((const float*)mask)[mi] != 0.f;
    else if (flag == 1) on = ((const int*)mask)[mi] != 0;
    else                on = ((const unsigned char*)mask)[mi] != 0;
    bv = on ? 0.f : -1e30f;
  }
  bias[idx] = bv;
}

// ---------------- fused bf16 GEMM: 128x256 tile, BK=32, 3-deep LDS, 2 blocks/CU ----------------
// One launch, 1048 blocks:
//   [0,520)     mode0: k   = xnl(33280x1024) @ WkT(512x1024)^T    -> k_h [b][h][j][d]
//   [520,1040)  mode2: v^T = WvT(512x1024)   @ xnl(33280x1024)^T  -> v_t [b][h][d][j]
//   [1040,1048) mode1: q   = ln(512 lat rows) @ WqT(512x1024)^T   -> q_h [b][h][i][d]
// 512 threads = 8 waves (2M x 4N), per-wave output 64x64 (4x4 16x16 frags).
// LDS 72 KiB (3 bufs) -> 2 blocks/CU; one barrier + counted vmcnt(3) per K-tile;
// stage distance 2 into the third buffer makes the single barrier race-free.
__global__ __launch_bounds__(512, 4) void gemm2_k(
    const u16* __restrict__ xnl, const u16* __restrict__ Wq_t,
    const u16* __restrict__ Wkv_t,
    u16* __restrict__ q_h, u16* __restrict__ k_h, u16* __restrict__ v_t)
{
  __shared__ __attribute__((aligned(16))) short As[3][4096];   // [buf][128r][32k]
  __shared__ __attribute__((aligned(16))) short Bs[3][8192];   // [buf][256r][32k]

  const int tid = threadIdx.x, lane = tid & 63;
  const int wid = tid >> 6, wr = wid >> 2, wc = wid & 3;
  const int l15 = lane & 15, lq = lane >> 4;

  const int bid = blockIdx.x;
  int mode, mblk, nblk;
  const u16 *Ap, *Bp;
  if (bid < 520)       { mode = 0; mblk = bid % 260; nblk = bid / 260; Ap = xnl; Bp = Wkv_t; }
  else if (bid < 1040) { const int r2 = bid - 520; mode = 2; mblk = r2 & 3; nblk = r2 >> 2;
                         Ap = Wkv_t + (size_t)512 * 1024; Bp = xnl; }
  else                 { const int r2 = bid - 1040; mode = 1; mblk = r2 >> 1; nblk = r2 & 1;
                         Ap = xnl; Bp = Wq_t; }
  const int m0 = mblk * 128, n0 = nblk * 256;

  // ---- stage constants: thread owns A granule (srow, sslot) and B granules (srow / srow+128, sslot)
  const int srow = tid >> 2, sslot = tid & 3;
  const u32 ss = (u32)((sslot ^ ((srow >> 1) & 3)) * 8);       // swizzled slot, in shorts
  const int gra = m0 + srow;
  const u32 arow = (mode == 1) ? ((u32)(gra >> 6) * 4160u + 4096u + (u32)(gra & 63)) : (u32)gra;
  const u32 aoff  = arow * 1024u + ss;
  const u32 boff0 = (u32)(n0 + srow) * 1024u + ss;
  const u32 boff1 = (u32)(n0 + 128 + srow) * 1024u + ss;       // (128+srow)>>1 & 3 == (srow>>1)&3

  // ---- read constants: swizzle folds to one per-thread value
  const int rsw = ((lq ^ ((l15 >> 1) & 3)) << 4);              // bytes
  const int aRd = wr * 4096 + l15 * 64 + rsw;                  // + buf*8192  + mi*1024
  const int bRd = wc * 4096 + l15 * 64 + rsw;                  // + buf*16384 + nj*1024

  const f32x4 z4 = {0.f, 0.f, 0.f, 0.f};
  f32x4 acc[4][4];
#pragma unroll
  for (int i = 0; i < 4; ++i)
#pragma unroll
    for (int j = 0; j < 4; ++j) acc[i][j] = z4;

  auto stage = [&](int buf, int T) {
    gload_lds16(Ap + aoff  + (u32)T * 32u, &As[buf][tid * 8]);
    gload_lds16(Bp + boff0 + (u32)T * 32u, &Bs[buf][tid * 8]);
    gload_lds16(Bp + boff1 + (u32)T * 32u, &Bs[buf][4096 + tid * 8]);
  };

  // prologue: stage tiles 0,1 into bufs 0,1; drain tile 0
  stage(0, 0);
  stage(1, 1);
  asm volatile("s_waitcnt vmcnt(3)" ::: "memory");
  __builtin_amdgcn_s_barrier();

  int c0 = 0, c1 = 1, c2 = 2;
#pragma unroll 1
  for (int t = 0; t < 32; ++t) {
    if (t < 30) stage(c2, t + 2);
    const char* aB = (const char*)&As[0][0] + c0 * 8192  + aRd;
    const char* bB = (const char*)&Bs[0][0] + c0 * 16384 + bRd;
    short8 af[4], bf[4];
#pragma unroll
    for (int mi = 0; mi < 4; ++mi) af[mi] = *(const short8*)(aB + mi * 1024);
#pragma unroll
    for (int nj = 0; nj < 4; ++nj) bf[nj] = *(const short8*)(bB + nj * 1024);
    __builtin_amdgcn_s_setprio(1);
#pragma unroll
    for (int mi = 0; mi < 4; ++mi)
#pragma unroll
      for (int nj = 0; nj < 4; ++nj)
        acc[mi][nj] = __builtin_amdgcn_mfma_f32_16x16x32_bf16(af[mi], bf[nj], acc[mi][nj], 0, 0, 0);
    __builtin_amdgcn_s_setprio(0);
    if (t < 30)       { asm volatile("s_waitcnt vmcnt(3)" ::: "memory"); }
    else if (t == 30) { asm volatile("s_waitcnt vmcnt(0)" ::: "memory"); }
    __builtin_amdgcn_s_barrier();
    const int tmp = c0; c0 = c1; c1 = c2; c2 = tmp;
  }

  // ---- epilogue: C write, per-wave 64x64 at (wr*64, wc*64)
#pragma unroll
  for (int mi = 0; mi < 4; ++mi)
#pragma unroll
    for (int nj = 0; nj < 4; ++nj)
#pragma unroll
      for (int r = 0; r < 4; ++r) {
        const int gm = m0 + wr * 64 + mi * 16 + lq * 4 + r;
        const int gn = n0 + wc * 64 + nj * 16 + l15;
        const u16 v = f2bf(acc[mi][nj][r]);
        if (mode == 0) {
          const int b = gm / 4160, j = gm - b * 4160;
          k_h[(((size_t)b * 8 + (gn >> 6)) * 4160 + j) * 64 + (gn & 63)] = v;
        } else if (mode == 2) {
          const int b = gn / 4160, j = gn - b * 4160;
          v_t[(((size_t)b * 8 + (gm >> 6)) * 64 + (gm & 63)) * 4160 + j] = v;
        } else {
          const int b = gm >> 6, i2 = gm & 63;
          q_h[(((size_t)b * 8 + (gn >> 6)) * 64 + i2) * 64 + (gn & 63)] = v;
        }
      }
}

// ---------------- flash attention, 512 blocks = (b,h) x 8 kv-splits ----------------
// S^T = K*q^T (so per-lane softmax state is one q row), O^T = V^T * P.
__global__ __launch_bounds__(256) void attn_k(
    const u16* __restrict__ q_h, const u16* __restrict__ k_h,
    const u16* __restrict__ v_t, const float* __restrict__ bias,
    float* __restrict__ O_part, float* __restrict__ m_part,
    float* __restrict__ l_part)
{
  __shared__ __attribute__((aligned(16))) short Ks[4096];   // swizzled [kv][d]
  __shared__ __attribute__((aligned(16))) short Vs[4096];   // swizzled [d][kv]
  __shared__ __attribute__((aligned(16))) short Ps[4][1152]; // per-wave P[q][kv], stride 72
  __shared__ float biasS[64];
  const int bid = blockIdx.x;
  const int sp = bid & 7, bh = bid >> 3;
  const int b = bh >> 3;
  const int tid = threadIdx.x, wid = tid >> 6, lane = tid & 63;
  const int t0 = sp ? (8 * sp + 1) : 0;
  const int tc = sp ? 8 : 9;                 // 9 + 7*8 = 65 tiles of 64 kv

  const size_t qoff = ((size_t)bh * 64 + wid * 16 + (lane & 15)) * 64 + 8 * (lane >> 4);
  const short8 qf0 = *(const short8*)&q_h[qoff];
  const short8 qf1 = *(const short8*)&q_h[qoff + 32];

  float mrun = -1e30f, lrun = 0.f;
  const f32x4 z4 = {0.f, 0.f, 0.f, 0.f};
  f32x4 o[4] = {z4, z4, z4, z4};
  const size_t khead = (size_t)bh * (4160 * 64);
  const size_t vhead = (size_t)bh * (64 * 4160);

  for (int tt = 0; tt < tc; ++tt) {
    const int t = t0 + tt;
    // stage K tile [64 kv][64 d], XOR-swizzled via pre-swizzled global source
#pragma unroll
    for (int p = 0; p < 2; ++p) {
      const int lo = (p * 256 + tid) * 16;
      const int row = lo >> 7;
      const int src = lo ^ ((row & 7) << 4);
      gload_lds16((const char*)k_h + (khead + (size_t)t * 4096) * 2 + src,
                  (char*)Ks + (p * 256 + wid * 64) * 16);
    }
    // stage V^T tile [64 d][64 kv] from v_t (row stride 4160)
#pragma unroll
    for (int p = 0; p < 2; ++p) {
      const int lo = (p * 256 + tid) * 16;
      const int row = lo >> 7;
      const int colb = (lo ^ ((row & 7) << 4)) & 127;
      gload_lds16((const char*)v_t + (vhead + (size_t)row * 4160 + t * 64) * 2 + colb,
                  (char*)Vs + (p * 256 + wid * 64) * 16);
    }
    if (tid < 64) biasS[tid] = bias[b * 4160 + t * 64 + tid];
    __syncthreads();

    // S^T = K * q^T : D[kv][q], kv = mi*16 + (lane>>4)*4 + r, q = lane&15
    f32x4 sc[4] = {z4, z4, z4, z4};
#pragma unroll
    for (int mi = 0; mi < 4; ++mi) {
      const int row = mi * 16 + (lane & 15);
      const int sw = (row & 7) << 4;
      short8 a0 = *(const short8*)((const char*)Ks + ((row * 128 + 16 * (lane >> 4)) ^ sw));
      sc[mi] = __builtin_amdgcn_mfma_f32_16x16x32_bf16(a0, qf0, sc[mi], 0, 0, 0);
      short8 a1 = *(const short8*)((const char*)Ks + ((row * 128 + 64 + 16 * (lane >> 4)) ^ sw));
      sc[mi] = __builtin_amdgcn_mfma_f32_16x16x32_bf16(a1, qf1, sc[mi], 0, 0, 0);
    }

    float sv[4][4];
    float tmax = -3e30f;
#pragma unroll
    for (int mi = 0; mi < 4; ++mi)
#pragma unroll
      for (int r = 0; r < 4; ++r) {
        const int kv = mi * 16 + (lane >> 4) * 4 + r;
        const float s = sc[mi][r] * (1.f / 64.f) + biasS[kv];
        sv[mi][r] = s;
        tmax = fmaxf(tmax, s);
      }
    tmax = fmaxf(tmax, __shfl_xor(tmax, 16));
    tmax = fmaxf(tmax, __shfl_xor(tmax, 32));
    const float mnew = fmaxf(mrun, tmax);
    const float fac = __expf(mrun - mnew);
    float psum = 0.f;
#pragma unroll
    for (int mi = 0; mi < 4; ++mi) {
      s16x4 pk;
#pragma unroll
      for (int r = 0; r < 4; ++r) {
        const float p = __expf(sv[mi][r] - mnew);
        psum += p;
        pk[r] = (short)f2bf(p);
      }
      *(s16x4*)&Ps[wid][(lane & 15) * 72 + mi * 16 + (lane >> 4) * 4] = pk;
    }
    psum += __shfl_xor(psum, 16);
    psum += __shfl_xor(psum, 32);
    lrun = lrun * fac + psum;
    mrun = mnew;
#pragma unroll
    for (int mi = 0; mi < 4; ++mi)
#pragma unroll
      for (int e = 0; e < 4; ++e) o[mi][e] *= fac;

    // O^T += V^T * P : D[d][q], d = mi*16 + (lane>>4)*4 + r, q = lane&15
#pragma unroll
    for (int mi = 0; mi < 4; ++mi) {
      const int row = mi * 16 + (lane & 15);
      const int sw = (row & 7) << 4;
      short8 a0 = *(const short8*)((const char*)Vs + ((row * 128 + 16 * (lane >> 4)) ^ sw));
      short8 p0 = *(const short8*)&Ps[wid][(lane & 15) * 72 + 8 * (lane >> 4)];
      o[mi] = __builtin_amdgcn_mfma_f32_16x16x32_bf16(a0, p0, o[mi], 0, 0, 0);
      short8 a1 = *(const short8*)((const char*)Vs + ((row * 128 + 64 + 16 * (lane >> 4)) ^ sw));
      short8 p1 = *(const short8*)&Ps[wid][(lane & 15) * 72 + 32 + 8 * (lane >> 4)];
      o[mi] = __builtin_amdgcn_mfma_f32_16x16x32_bf16(a1, p1, o[mi], 0, 0, 0);
    }
    __syncthreads();
  }

#pragma unroll
  for (int mi = 0; mi < 4; ++mi)
#pragma unroll
    for (int r = 0; r < 4; ++r) {
      const int d = mi * 16 + (lane >> 4) * 4 + r;
      const int q = wid * 16 + (lane & 15);
      O_part[(((size_t)sp * 64 + bh) * 64 + d) * 64 + q] = o[mi][r];
    }
  if (lane < 16) {
    m_part[((size_t)sp * 64 + bh) * 64 + wid * 16 + lane] = mrun;
    l_part[((size_t)sp * 64 + bh) * 64 + wid * 16 + lane] = lrun;
  }
}

// ---------------- split-softmax combine -> attn_out [b][i][h*64+d] f32 ----------------
__global__ __launch_bounds__(256) void combine_k(
    const float* __restrict__ O_part, const float* __restrict__ m_part,
    const float* __restrict__ l_part, float* __restrict__ attn_out)
{
  __shared__ float wgt[8][64];
  const int bh = blockIdx.x;
  const int b = bh >> 3, h = bh & 7;
  const int t = threadIdx.x;
  if (t < 64) {
    float mv[8], lv[8];
#pragma unroll
    for (int s = 0; s < 8; ++s) {
      mv[s] = m_part[((size_t)s * 64 + bh) * 64 + t];
      lv[s] = l_part[((size_t)s * 64 + bh) * 64 + t];
    }
    float M = mv[0];
#pragma unroll
    for (int s = 1; s < 8; ++s) M = fmaxf(M, mv[s]);
    float den = 0.f;
#pragma unroll
    for (int s = 0; s < 8; ++s) den += lv[s] * __expf(mv[s] - M);
    const float inv = 1.f / den;
#pragma unroll
    for (int s = 0; s < 8; ++s) wgt[s][t] = __expf(mv[s] - M) * inv;
  }
  __syncthreads();
#pragma unroll
  for (int i = 0; i < 16; ++i) {
    const int p = i * 256 + t;
    const int d = p >> 6, q = p & 63;
    float acc = 0.f;
#pragma unroll
    for (int s = 0; s < 8; ++s)
      acc += O_part[(((size_t)s * 64 + bh) * 64 + d) * 64 + q] * wgt[s][q];
    attn_out[((size_t)b * 64 + q) * 512 + h * 64 + d] = acc;
  }
}

// ---------------- out = LN(attn_out @ Wo), 2 rows per block ----------------
__global__ __launch_bounds__(256) void outproj_k(
    const float* __restrict__ attn_out, const float* __restrict__ Wo,
    const float* __restrict__ g, const float* __restrict__ be,
    float* __restrict__ out)
{
  __shared__ float arow[2][512];
  __shared__ float red[8];
  const int rb = blockIdx.x * 2, t = threadIdx.x;
  arow[0][t]       = attn_out[(size_t)rb * 512 + t];
  arow[0][t + 256] = attn_out[(size_t)rb * 512 + 256 + t];
  arow[1][t]       = attn_out[(size_t)(rb + 1) * 512 + t];
  arow[1][t + 256] = attn_out[(size_t)(rb + 1) * 512 + 256 + t];
  __syncthreads();
  float a0x = 0, a0y = 0, a0z = 0, a0w = 0;
  float a1x = 0, a1y = 0, a1z = 0, a1w = 0;
  for (int k = 0; k < 512; ++k) {
    const float4 w = *(const float4*)(Wo + (size_t)k * 1024 + t * 4);
    const float x0 = arow[0][k], x1 = arow[1][k];
    a0x += x0 * w.x; a0y += x0 * w.y; a0z += x0 * w.z; a0w += x0 * w.w;
    a1x += x1 * w.x; a1y += x1 * w.y; a1z += x1 * w.z; a1w += x1 * w.w;
  }
  const float4 gv = *(const float4*)(g + t * 4);
  const float4 bv = *(const float4*)(be + t * 4);
  {
    float s1 = a0x + a0y + a0z + a0w;
    float s2 = a0x * a0x + a0y * a0y + a0z * a0z + a0w * a0w;
    block_reduce2(s1, s2, red);
    const float mean = s1 * (1.f / 1024.f);
    const float rstd = rsqrtf(s2 * (1.f / 1024.f) - mean * mean + 1e-5f);
    float4 ov;
    ov.x = (a0x - mean) * rstd * gv.x + bv.x;
    ov.y = (a0y - mean) * rstd * gv.y + bv.y;
    ov.z = (a0z - mean) * rstd * gv.z + bv.z;
    ov.w = (a0w - mean) * rstd * gv.w + bv.w;
    *(float4*)(out + (size_t)rb * 1024 + t * 4) = ov;
  }
  {
    float s1 = a1x + a1y + a1z + a1w;
    float s2 = a1x * a1x + a1y * a1y + a1z * a1z + a1w * a1w;
    block_reduce2(s1, s2, red);
    const float mean = s1 * (1.f / 1024.f);
    const float rstd = rsqrtf(s2 * (1.f / 1024.f) - mean * mean + 1e-5f);
    float4 ov;
    ov.x = (a1x - mean) * rstd * gv.x + bv.x;
    ov.y = (a1y - mean) * rstd * gv.y + bv.y;
    ov.z = (a1z - mean) * rstd * gv.z + bv.z;
    ov.w = (a1w - mean) * rstd * gv.w + bv.w;
    *(float4*)(out + (size_t)(rb + 1) * 1024 + t * 4) = ov;
  }
}

extern "C" void kernel_launch(void* const* d_in, const int* in_sizes, int n_in,
                              void* d_out, int out_size, void* d_ws, size_t ws_size,
                              hipStream_t stream) {
  (void)in_sizes; (void)n_in; (void)out_size; (void)ws_size;
  const float* x       = (const float*)d_in[0];
  const float* latents = (const float*)d_in[1];
  const void*  mask    = d_in[2];
  const float* Wq      = (const float*)d_in[3];
  const float* Wkv     = (const float*)d_in[4];
  const float* Wo      = (const float*)d_in[5];
  const float* gx      = (const float*)d_in[6];
  const float* bx      = (const float*)d_in[7];
  const float* gl      = (const float*)d_in[8];
  const float* bl      = (const float*)d_in[9];
  const float* go      = (const float*)d_in[10];
  const float* bo      = (const float*)d_in[11];
  float* out = (float*)d_out;

  char* w = (char*)d_ws;
  u16* xnl   = (u16*)w; w += (size_t)33280 * 1024 * 2;       // LN'd concat rows, bf16
  u16* Wq_t  = (u16*)w; w += (size_t)512 * 1024 * 2;         // Wq^T bf16
  u16* Wkv_t = (u16*)w; w += (size_t)1024 * 1024 * 2;        // Wkv^T bf16
  u16* q_h   = (u16*)w; w += (size_t)8 * 8 * 64 * 64 * 2;    // [b][h][i][d]
  u16* k_h   = (u16*)w; w += (size_t)8 * 8 * 4160 * 64 * 2;  // [b][h][j][d]
  u16* v_t   = (u16*)w; w += (size_t)8 * 8 * 64 * 4160 * 2;  // [b][h][d][j]
  float* bias   = (float*)w; w += (size_t)8 * 4160 * 4;
  float* O_part = (float*)w; w += (size_t)8 * 64 * 64 * 64 * 4;
  float* m_part = (float*)w; w += (size_t)8 * 64 * 64 * 4;
  float* l_part = (float*)w; w += (size_t)8 * 64 * 64 * 4;
  float* attnO  = (float*)w; w += (size_t)512 * 512 * 4;

  transpose_w_k<<<dim3(16, 32), dim3(32, 8), 0, stream>>>(Wq, Wq_t, 1024, 512);
  transpose_w_k<<<dim3(32, 32), dim3(32, 8), 0, stream>>>(Wkv, Wkv_t, 1024, 1024);
  ln_rows_k<<<dim3(32768), dim3(256), 0, stream>>>(x, gx, bx, xnl, 0);
  ln_rows_k<<<dim3(512), dim3(256), 0, stream>>>(latents, gl, bl, xnl, 1);
  mask_bias_k<<<dim3(130), dim3(256), 0, stream>>>(mask, bias);
  gemm2_k<<<dim3(1048), dim3(512), 0, stream>>>(xnl, Wq_t, Wkv_t, q_h, k_h, v_t);
  attn_k<<<dim3(512), dim3(256), 0, stream>>>(q_h, k_h, v_t, bias, O_part, m_part, l_part);
  combine_k<<<dim3(64), dim3(256), 0, stream>>>(O_part, m_part, l_part, attnO);
  outproj_k<<<dim3(256), dim3(256), 0, stream>>>(attnO, Wo, go, bo, out);
}